// Round 1
// baseline (699.540 us; speedup 1.0000x reference)
//
#include <hip/hip_runtime.h>
#include <hip/hip_bf16.h>

#define B_   8
#define CIN  128
#define COUT 64
#define NPIX 4096

// ---------------------------------------------------------------------------
// Kernel A: fused Q/K/V 1x1-conv projections.
// grid (NPIX/256, COUT/8, B), block 256. Each thread: one n, 8 output rows,
// 3 matrices. Weights staged in LDS (broadcast reads), x loads coalesced.
// ---------------------------------------------------------------------------
__global__ __launch_bounds__(256) void qkv_proj_kernel(
    const float* __restrict__ x,
    const float* __restrict__ wq, const float* __restrict__ bq,
    const float* __restrict__ wk, const float* __restrict__ bk,
    const float* __restrict__ wv, const float* __restrict__ bv,
    float* __restrict__ q, float* __restrict__ k, float* __restrict__ v)
{
    const int n  = blockIdx.x * 256 + threadIdx.x;
    const int og = blockIdx.y;
    const int b  = blockIdx.z;

    __shared__ float s_wq[8][CIN];
    __shared__ float s_wk[8][CIN];
    __shared__ float s_wv[8][CIN];

    for (int t = threadIdx.x; t < 8 * CIN; t += 256) {
        const int r = t >> 7, c = t & 127;
        const int o = (og << 3) + r;
        s_wq[r][c] = wq[o * CIN + c];
        s_wk[r][c] = wk[o * CIN + c];
        s_wv[r][c] = wv[o * CIN + c];
    }
    __syncthreads();

    float aq[8] = {}, ak[8] = {}, av[8] = {};
    const float* xb = x + (size_t)b * CIN * NPIX + n;

    for (int c = 0; c < CIN; c += 4) {
        const float x0 = xb[(size_t)(c + 0) * NPIX];
        const float x1 = xb[(size_t)(c + 1) * NPIX];
        const float x2 = xb[(size_t)(c + 2) * NPIX];
        const float x3 = xb[(size_t)(c + 3) * NPIX];
#pragma unroll
        for (int r = 0; r < 8; ++r) {
            const float4 wq4 = *(const float4*)&s_wq[r][c];
            const float4 wk4 = *(const float4*)&s_wk[r][c];
            const float4 wv4 = *(const float4*)&s_wv[r][c];
            aq[r] += wq4.x * x0 + wq4.y * x1 + wq4.z * x2 + wq4.w * x3;
            ak[r] += wk4.x * x0 + wk4.y * x1 + wk4.z * x2 + wk4.w * x3;
            av[r] += wv4.x * x0 + wv4.y * x1 + wv4.z * x2 + wv4.w * x3;
        }
    }
#pragma unroll
    for (int r = 0; r < 8; ++r) {
        const int o = (og << 3) + r;
        const size_t idx = ((size_t)b * COUT + o) * NPIX + n;
        q[idx] = aq[r] + bq[o];
        k[idx] = ak[r] + bk[o];
        v[idx] = av[r] + bv[o];
    }
}

// ---------------------------------------------------------------------------
// Kernel B: flash-style fused attention (fp32).
// grid (NPIX/64, B), block 256 = 16x16 threads, 4x4 register tile each.
// Per block: 64 Q rows (one i-tile), loop over 64-wide j-tiles with online
// softmax. Q/K staged [o][i]-major; V and P staged j-major (padded rows) so
// both GEMMs read contiguous float4 from LDS.
// ---------------------------------------------------------------------------
__global__ __launch_bounds__(256) void flash_attn_kernel(
    const float* __restrict__ q, const float* __restrict__ k,
    const float* __restrict__ v, float* __restrict__ att)
{
    const int b   = blockIdx.y;
    const int i0  = blockIdx.x * 64;
    const int tid = threadIdx.x;
    const int ti  = tid >> 4, tj = tid & 15;

    __shared__ float s_q [64][64];   // [o][i]
    __shared__ float s_k [64][64];   // [o][j]
    __shared__ float s_vt[64][68];   // [j][o], padded (16B-aligned rows)
    __shared__ float s_p [64][68];   // [j][i], padded

    const float scale = 0.088388347648318447f;  // 1/sqrt(C_IN=128)

    for (int t = tid; t < 64 * 64; t += 256) {
        const int o = t >> 6, i = t & 63;
        s_q[o][i] = q[((size_t)b * COUT + o) * NPIX + i0 + i];
    }

    float acc[4][4] = {};
    float m_i[4], l_i[4];
#pragma unroll
    for (int r = 0; r < 4; ++r) { m_i[r] = -1e30f; l_i[r] = 0.f; }

    __syncthreads();

    for (int j0 = 0; j0 < NPIX; j0 += 64) {
        // stage K and V^T tiles
        for (int t = tid; t < 64 * 64; t += 256) {
            const int o = t >> 6, j = t & 63;
            const size_t g = ((size_t)b * COUT + o) * NPIX + j0 + j;
            s_k[o][j]  = k[g];
            s_vt[j][o] = v[g];
        }
        __syncthreads();

        // S = Q^T K  (64x64 tile, reduce over o=0..63)
        float s[4][4] = {};
#pragma unroll 4
        for (int o = 0; o < COUT; ++o) {
            const float4 q4 = *(const float4*)&s_q[o][ti << 2];
            const float4 k4 = *(const float4*)&s_k[o][tj << 2];
            const float qa[4] = {q4.x, q4.y, q4.z, q4.w};
            const float ka[4] = {k4.x, k4.y, k4.z, k4.w};
#pragma unroll
            for (int r = 0; r < 4; ++r)
#pragma unroll
                for (int c = 0; c < 4; ++c)
                    s[r][c] += qa[r] * ka[c];
        }

        // online softmax over this j-tile; rows i = 4*ti+r owned by the 16
        // threads sharing ti (lanes differing only in bits 0..3 -> shfl_xor)
#pragma unroll
        for (int r = 0; r < 4; ++r) {
#pragma unroll
            for (int c = 0; c < 4; ++c) s[r][c] *= scale;
            float mx = fmaxf(fmaxf(s[r][0], s[r][1]), fmaxf(s[r][2], s[r][3]));
#pragma unroll
            for (int off = 1; off < 16; off <<= 1)
                mx = fmaxf(mx, __shfl_xor(mx, off));
            const float mnew  = fmaxf(m_i[r], mx);
            const float alpha = __expf(m_i[r] - mnew);
            float pr[4], ls = 0.f;
#pragma unroll
            for (int c = 0; c < 4; ++c) { pr[c] = __expf(s[r][c] - mnew); ls += pr[c]; }
#pragma unroll
            for (int off = 1; off < 16; off <<= 1)
                ls += __shfl_xor(ls, off);
            m_i[r] = mnew;
            l_i[r] = l_i[r] * alpha + ls;
#pragma unroll
            for (int c = 0; c < 4; ++c) {
                acc[r][c] *= alpha;                       // rescale O rows
                s_p[(tj << 2) + c][(ti << 2) + r] = pr[c]; // P^T stage [j][i]
            }
        }
        __syncthreads();

        // O[i][o] += P[i][j] * V[o][j]  (reduce over tile j)
#pragma unroll 4
        for (int j = 0; j < 64; ++j) {
            const float4 p4 = *(const float4*)&s_p[j][ti << 2];
            const float4 v4 = *(const float4*)&s_vt[j][tj << 2];
            const float pa[4] = {p4.x, p4.y, p4.z, p4.w};
            const float va[4] = {v4.x, v4.y, v4.z, v4.w};
#pragma unroll
            for (int r = 0; r < 4; ++r)
#pragma unroll
                for (int c = 0; c < 4; ++c)
                    acc[r][c] += pa[r] * va[c];
        }
        __syncthreads();
    }

    // normalize, restage to [o][i], coalesced write of att[b][o][i0+i]
#pragma unroll
    for (int r = 0; r < 4; ++r) {
        const float inv = 1.f / l_i[r];
#pragma unroll
        for (int c = 0; c < 4; ++c)
            s_p[(tj << 2) + c][(ti << 2) + r] = acc[r][c] * inv;
    }
    __syncthreads();
    for (int t = tid; t < 64 * 64; t += 256) {
        const int o = t >> 6, i = t & 63;
        att[((size_t)b * COUT + o) * NPIX + i0 + i] = s_p[o][i];
    }
}

// ---------------------------------------------------------------------------
// Kernel C: output projection + gamma-gated residual.
// grid (NPIX/256, CIN/8, B), block 256.
// ---------------------------------------------------------------------------
__global__ __launch_bounds__(256) void out_proj_kernel(
    const float* __restrict__ att, const float* __restrict__ wo,
    const float* __restrict__ bo, const float* __restrict__ gamma,
    const float* __restrict__ x, float* __restrict__ y)
{
    const int n  = blockIdx.x * 256 + threadIdx.x;
    const int cg = blockIdx.y;
    const int b  = blockIdx.z;

    __shared__ float s_wo[8][COUT];
    for (int t = threadIdx.x; t < 8 * COUT; t += 256) {
        const int r = t >> 6, o = t & 63;
        s_wo[r][o] = wo[((cg << 3) + r) * COUT + o];
    }
    __syncthreads();

    float a[8] = {};
    const float* ab = att + (size_t)b * COUT * NPIX + n;
    for (int o = 0; o < COUT; o += 4) {
        const float v0 = ab[(size_t)(o + 0) * NPIX];
        const float v1 = ab[(size_t)(o + 1) * NPIX];
        const float v2 = ab[(size_t)(o + 2) * NPIX];
        const float v3 = ab[(size_t)(o + 3) * NPIX];
#pragma unroll
        for (int r = 0; r < 8; ++r) {
            const float4 w4 = *(const float4*)&s_wo[r][o];
            a[r] += w4.x * v0 + w4.y * v1 + w4.z * v2 + w4.w * v3;
        }
    }
    const float g = gamma[0];
#pragma unroll
    for (int r = 0; r < 8; ++r) {
        const int c = (cg << 3) + r;
        const size_t idx = ((size_t)b * CIN + c) * NPIX + n;
        y[idx] = g * (a[r] + bo[c]) + x[idx];
    }
}

extern "C" void kernel_launch(void* const* d_in, const int* in_sizes, int n_in,
                              void* d_out, int out_size, void* d_ws, size_t ws_size,
                              hipStream_t stream)
{
    const float* x     = (const float*)d_in[0];
    const float* wq    = (const float*)d_in[1];
    const float* bq    = (const float*)d_in[2];
    const float* wk    = (const float*)d_in[3];
    const float* bk    = (const float*)d_in[4];
    const float* wv    = (const float*)d_in[5];
    const float* bv    = (const float*)d_in[6];
    const float* wo    = (const float*)d_in[7];
    const float* bo    = (const float*)d_in[8];
    const float* gamma = (const float*)d_in[9];
    float* out = (float*)d_out;

    const size_t plane = (size_t)B_ * COUT * NPIX;   // 2M elements
    float* q   = (float*)d_ws;
    float* k   = q + plane;
    float* v   = k + plane;
    float* att = v + plane;                          // total 33.6 MB of ws

    qkv_proj_kernel<<<dim3(NPIX / 256, COUT / 8, B_), 256, 0, stream>>>(
        x, wq, bq, wk, bk, wv, bv, q, k, v);
    flash_attn_kernel<<<dim3(NPIX / 64, B_), 256, 0, stream>>>(q, k, v, att);
    out_proj_kernel<<<dim3(NPIX / 256, CIN / 8, B_), 256, 0, stream>>>(
        att, wo, bo, gamma, x, out);
}

// Round 5
// 291.155 us; speedup vs baseline: 2.4026x; 2.4026x over previous
//
#include <hip/hip_runtime.h>
#include <hip/hip_bf16.h>

#define B_   8
#define CIN  128
#define COUT 64
#define NPIX 4096

typedef __attribute__((ext_vector_type(8))) short short8;
typedef __attribute__((ext_vector_type(4))) float f32x4;

// f32 -> bf16 round-to-nearest-even
__device__ __forceinline__ unsigned short f2bf(float f) {
    union { float f; unsigned int u; } x; x.f = f;
    return (unsigned short)((x.u + 0x7FFF + ((x.u >> 16) & 1)) >> 16);
}

// ---------------------------------------------------------------------------
// Kernel A: fused Q/K/V 1x1-conv projections -> bf16, attention-ready layouts.
//   qt[b][n][64]  = (q + bq) * 1/sqrt(CIN)   (row-major in d: A-frag layout)
//   kt[b][n][64]  = (k + bk)                 (row-major in d: B-frag layout)
//   vb[b][o][n]   = (v + bv)                 (j-contiguous: B-frag for PV)
// grid (NPIX/256, COUT/8, B), block 256.
// ---------------------------------------------------------------------------
__global__ __launch_bounds__(256) void qkv_proj_kernel(
    const float* __restrict__ x,
    const float* __restrict__ wq, const float* __restrict__ bq,
    const float* __restrict__ wk, const float* __restrict__ bk,
    const float* __restrict__ wv, const float* __restrict__ bv,
    unsigned short* __restrict__ qt, unsigned short* __restrict__ kt,
    unsigned short* __restrict__ vb)
{
    const int n  = blockIdx.x * 256 + threadIdx.x;
    const int og = blockIdx.y;
    const int b  = blockIdx.z;

    __shared__ float s_wq[8][CIN];
    __shared__ float s_wk[8][CIN];
    __shared__ float s_wv[8][CIN];

    for (int t = threadIdx.x; t < 8 * CIN; t += 256) {
        const int r = t >> 7, c = t & 127;
        const int o = (og << 3) + r;
        s_wq[r][c] = wq[o * CIN + c];
        s_wk[r][c] = wk[o * CIN + c];
        s_wv[r][c] = wv[o * CIN + c];
    }
    __syncthreads();

    float aq[8] = {}, ak[8] = {}, av[8] = {};
    const float* xb = x + (size_t)b * CIN * NPIX + n;

    for (int c = 0; c < CIN; c += 4) {
        const float x0 = xb[(size_t)(c + 0) * NPIX];
        const float x1 = xb[(size_t)(c + 1) * NPIX];
        const float x2 = xb[(size_t)(c + 2) * NPIX];
        const float x3 = xb[(size_t)(c + 3) * NPIX];
#pragma unroll
        for (int r = 0; r < 8; ++r) {
            const float4 wq4 = *(const float4*)&s_wq[r][c];
            const float4 wk4 = *(const float4*)&s_wk[r][c];
            const float4 wv4 = *(const float4*)&s_wv[r][c];
            aq[r] += wq4.x * x0 + wq4.y * x1 + wq4.z * x2 + wq4.w * x3;
            ak[r] += wk4.x * x0 + wk4.y * x1 + wk4.z * x2 + wk4.w * x3;
            av[r] += wv4.x * x0 + wv4.y * x1 + wv4.z * x2 + wv4.w * x3;
        }
    }

    const float scale = 0.08838834764831845f;  // 1/sqrt(CIN)
    short8 qv, kv;
#pragma unroll
    for (int r = 0; r < 8; ++r) {
        const int o = (og << 3) + r;
        qv[r] = (short)f2bf((aq[r] + bq[o]) * scale);
        kv[r] = (short)f2bf(ak[r] + bk[o]);
        vb[((size_t)(b * COUT + o)) * NPIX + n] = f2bf(av[r] + bv[o]);
    }
    *(short8*)&qt[((size_t)(b * NPIX + n)) * 64 + (og << 3)] = qv;
    *(short8*)&kt[((size_t)(b * NPIX + n)) * 64 + (og << 3)] = kv;
}

// ---------------------------------------------------------------------------
// Kernel B: flash attention on MFMA (bf16 in, fp32 accum).
// grid (NPIX/64, B), block 256 = 4 waves. Wave w owns Q rows [w*16, w*16+16).
// Per k-tile (64 j): QK^T = 8 mfma_16x16x32, online softmax (16-lane shfl
// groups), P via per-wave LDS slice, PV = 8 mfma. 2 barriers per tile.
// Fragment maps (m89-verified): A/B: m|n = lane&15, k = (lane>>4)*8 + i;
// C/D: col = lane&15, row = (lane>>4)*4 + reg.
// LDS rows padded to 72 (144B = 36 banks -> +4 bank rotation/row).
// p_lds rows are wave-private; same-wave DS RAW is in-order -> no barrier.
// ---------------------------------------------------------------------------
__global__ __launch_bounds__(256) void flash_attn_mfma_kernel(
    const unsigned short* __restrict__ qt,
    const unsigned short* __restrict__ kt,
    const unsigned short* __restrict__ vb,
    float* __restrict__ att)
{
    const int b    = blockIdx.y;
    const int i0   = blockIdx.x * 64;
    const int tid  = threadIdx.x;
    const int lane = tid & 63;
    const int wave = tid >> 6;
    const int l16  = lane & 15;
    const int lh   = lane >> 4;   // 0..3

    __shared__ __align__(16) unsigned short q_lds[64][72];  // [i][d]
    __shared__ __align__(16) unsigned short k_lds[64][72];  // [j][d]
    __shared__ __align__(16) unsigned short v_lds[64][72];  // [o][j]
    __shared__ __align__(16) unsigned short p_lds[64][72];  // [i][j], wave-private 16-row slices

    // stage Q tile [64 rows][64 d], fully coalesced 16B chunks
    for (int t = tid; t < 512; t += 256) {
        const int row = t >> 3, c8 = (t & 7) * 8;
        *(short8*)&q_lds[row][c8] =
            *(const short8*)&qt[((size_t)(b * NPIX + i0 + row)) * 64 + c8];
    }
    __syncthreads();

    // Q A-fragments are k-loop invariant: preload
    short8 aq0 = *(const short8*)&q_lds[wave * 16 + l16][lh * 8];
    short8 aq1 = *(const short8*)&q_lds[wave * 16 + l16][32 + lh * 8];

    f32x4 acc[4] = {};          // [o-subtile][reg]
    float m_i[4], l_i[4];
#pragma unroll
    for (int r = 0; r < 4; ++r) { m_i[r] = -3.0e38f; l_i[r] = 0.f; }

    for (int j0 = 0; j0 < NPIX; j0 += 64) {
        // stage K [j][d] and V [o][j] tiles (coalesced 16B chunks)
        for (int t = tid; t < 512; t += 256) {
            const int row = t >> 3, c8 = (t & 7) * 8;
            *(short8*)&k_lds[row][c8] =
                *(const short8*)&kt[((size_t)(b * NPIX + j0 + row)) * 64 + c8];
            *(short8*)&v_lds[row][c8] =
                *(const short8*)&vb[((size_t)(b * COUT + row)) * NPIX + j0 + c8];
        }
        __syncthreads();

        // S = Q^T K : 4 j-subtiles x 2 K-halves
        f32x4 s[4] = {};
#pragma unroll
        for (int js = 0; js < 4; ++js) {
            short8 bk0 = *(const short8*)&k_lds[js * 16 + l16][lh * 8];
            short8 bk1 = *(const short8*)&k_lds[js * 16 + l16][32 + lh * 8];
            s[js] = __builtin_amdgcn_mfma_f32_16x16x32_bf16(aq0, bk0, s[js], 0, 0, 0);
            s[js] = __builtin_amdgcn_mfma_f32_16x16x32_bf16(aq1, bk1, s[js], 0, 0, 0);
        }

        // online softmax: row i = wave*16 + lh*4 + r, cols spread over
        // 16-lane group (lane&15) x 4 subtiles
#pragma unroll
        for (int r = 0; r < 4; ++r) {
            float mx = fmaxf(fmaxf(s[0][r], s[1][r]), fmaxf(s[2][r], s[3][r]));
            mx = fmaxf(mx, __shfl_xor(mx, 1));
            mx = fmaxf(mx, __shfl_xor(mx, 2));
            mx = fmaxf(mx, __shfl_xor(mx, 4));
            mx = fmaxf(mx, __shfl_xor(mx, 8));
            const float mnew  = fmaxf(m_i[r], mx);
            const float alpha = __expf(m_i[r] - mnew);
            const int prow = wave * 16 + lh * 4 + r;
            float ps = 0.f;
#pragma unroll
            for (int js = 0; js < 4; ++js) {
                const float p = __expf(s[js][r] - mnew);
                ps += p;
                p_lds[prow][js * 16 + l16] = f2bf(p);
            }
            ps += __shfl_xor(ps, 1);
            ps += __shfl_xor(ps, 2);
            ps += __shfl_xor(ps, 4);
            ps += __shfl_xor(ps, 8);
            m_i[r] = mnew;
            l_i[r] = l_i[r] * alpha + ps;
#pragma unroll
            for (int os = 0; os < 4; ++os) acc[os][r] *= alpha;
        }

        // O += P V : same-wave p_lds RAW (in-order DS, no barrier needed)
        short8 ap0 = *(const short8*)&p_lds[wave * 16 + l16][lh * 8];
        short8 ap1 = *(const short8*)&p_lds[wave * 16 + l16][32 + lh * 8];
#pragma unroll
        for (int os = 0; os < 4; ++os) {
            short8 bv0 = *(const short8*)&v_lds[os * 16 + l16][lh * 8];
            short8 bv1 = *(const short8*)&v_lds[os * 16 + l16][32 + lh * 8];
            acc[os] = __builtin_amdgcn_mfma_f32_16x16x32_bf16(ap0, bv0, acc[os], 0, 0, 0);
            acc[os] = __builtin_amdgcn_mfma_f32_16x16x32_bf16(ap1, bv1, acc[os], 0, 0, 0);
        }
        __syncthreads();   // protect k_lds/v_lds before next stage
    }

    // normalize + write att[b][o][i] (fp32)
#pragma unroll
    for (int r = 0; r < 4; ++r) {
        const float inv = 1.f / l_i[r];
        const int i = i0 + wave * 16 + lh * 4 + r;
#pragma unroll
        for (int os = 0; os < 4; ++os) {
            att[((size_t)(b * COUT + os * 16 + l16)) * NPIX + i] = acc[os][r] * inv;
        }
    }
}

// ---------------------------------------------------------------------------
// Kernel C: output projection + gamma-gated residual (unchanged).
// ---------------------------------------------------------------------------
__global__ __launch_bounds__(256) void out_proj_kernel(
    const float* __restrict__ att, const float* __restrict__ wo,
    const float* __restrict__ bo, const float* __restrict__ gamma,
    const float* __restrict__ x, float* __restrict__ y)
{
    const int n  = blockIdx.x * 256 + threadIdx.x;
    const int cg = blockIdx.y;
    const int b  = blockIdx.z;

    __shared__ float s_wo[8][COUT];
    for (int t = threadIdx.x; t < 8 * COUT; t += 256) {
        const int r = t >> 6, o = t & 63;
        s_wo[r][o] = wo[((cg << 3) + r) * COUT + o];
    }
    __syncthreads();

    float a[8] = {};
    const float* ab = att + (size_t)b * COUT * NPIX + n;
    for (int o = 0; o < COUT; o += 4) {
        const float v0 = ab[(size_t)(o + 0) * NPIX];
        const float v1 = ab[(size_t)(o + 1) * NPIX];
        const float v2 = ab[(size_t)(o + 2) * NPIX];
        const float v3 = ab[(size_t)(o + 3) * NPIX];
#pragma unroll
        for (int r = 0; r < 8; ++r) {
            const float4 w4 = *(const float4*)&s_wo[r][o];
            a[r] += w4.x * v0 + w4.y * v1 + w4.z * v2 + w4.w * v3;
        }
    }
    const float g = gamma[0];
#pragma unroll
    for (int r = 0; r < 8; ++r) {
        const int c = (cg << 3) + r;
        const size_t idx = ((size_t)b * CIN + c) * NPIX + n;
        y[idx] = g * (a[r] + bo[c]) + x[idx];
    }
}

extern "C" void kernel_launch(void* const* d_in, const int* in_sizes, int n_in,
                              void* d_out, int out_size, void* d_ws, size_t ws_size,
                              hipStream_t stream)
{
    const float* x     = (const float*)d_in[0];
    const float* wq    = (const float*)d_in[1];
    const float* bq    = (const float*)d_in[2];
    const float* wk    = (const float*)d_in[3];
    const float* bk    = (const float*)d_in[4];
    const float* wv    = (const float*)d_in[5];
    const float* bv    = (const float*)d_in[6];
    const float* wo    = (const float*)d_in[7];
    const float* bo    = (const float*)d_in[8];
    const float* gamma = (const float*)d_in[9];
    float* out = (float*)d_out;

    const size_t plane = (size_t)B_ * NPIX * 64;     // 2M elems
    unsigned short* qt = (unsigned short*)d_ws;      // 4 MB
    unsigned short* kt = qt + plane;                 // 4 MB
    unsigned short* vb = kt + plane;                 // 4 MB
    float*         att = (float*)(vb + plane);       // 8 MB fp32

    qkv_proj_kernel<<<dim3(NPIX / 256, COUT / 8, B_), 256, 0, stream>>>(
        x, wq, bq, wk, bk, wv, bv, qt, kt, vb);
    flash_attn_mfma_kernel<<<dim3(NPIX / 64, B_), 256, 0, stream>>>(qt, kt, vb, att);
    out_proj_kernel<<<dim3(NPIX / 256, CIN / 8, B_), 256, 0, stream>>>(
        att, wo, bo, gamma, x, out);
}

// Round 8
// 250.942 us; speedup vs baseline: 2.7877x; 1.1602x over previous
//
#include <hip/hip_runtime.h>
#include <hip/hip_bf16.h>

#define B_   8
#define CIN  128
#define COUT 64
#define NPIX 4096

typedef __attribute__((ext_vector_type(8))) short short8;
typedef __attribute__((ext_vector_type(4))) float f32x4;

// f32 -> bf16 round-to-nearest-even
__device__ __forceinline__ unsigned short f2bf(float f) {
    union { float f; unsigned int u; } x; x.f = f;
    return (unsigned short)((x.u + 0x7FFF + ((x.u >> 16) & 1)) >> 16);
}

// ---------------------------------------------------------------------------
// Kernel A: Q/K/V projections, single-pass over x (read 1x, staged in LDS).
// grid (NPIX/64, B), block 256 = 4 waves. Wave w computes 48 of the 192
// stacked output rows [q;k;v] for 64 pixels; weight reads are wave-uniform
// (scalarized). q/k go through an LDS transpose to [n][d] bf16 layout.
// ---------------------------------------------------------------------------
__global__ __launch_bounds__(256) void qkv_proj_kernel(
    const float* __restrict__ x,
    const float* __restrict__ wq, const float* __restrict__ bq,
    const float* __restrict__ wk, const float* __restrict__ bk,
    const float* __restrict__ wv, const float* __restrict__ bv,
    unsigned short* __restrict__ qt, unsigned short* __restrict__ kt,
    unsigned short* __restrict__ vb)
{
    const int n0   = blockIdx.x * 64;
    const int b    = blockIdx.y;
    const int tid  = threadIdx.x;
    const int wave = tid >> 6;
    const int lane = tid & 63;

    __shared__ __align__(16) float xt[CIN][64];            // 32 KB
    __shared__ __align__(16) unsigned short tr[2][64][72]; // 18 KB (q,k transpose)

    for (int idx = tid; idx < CIN * 64; idx += 256) {
        const int c = idx >> 6, n = idx & 63;
        xt[c][n] = x[((size_t)(b * CIN + c)) * NPIX + n0 + n];
    }
    __syncthreads();

    const float scale = 0.08838834764831845f;  // 1/sqrt(CIN)
    const int obase = wave * 48;

    for (int g = 0; g < 6; ++g) {
        const int og0  = obase + g * 8;        // 8-aligned, never straddles 64
        const int mi   = og0 >> 6;             // 0=q 1=k 2=v (wave-uniform)
        const int row0 = og0 & 63;
        const float* wsel = (mi == 0) ? wq : ((mi == 1) ? wk : wv);
        const float* bsel = (mi == 0) ? bq : ((mi == 1) ? bk : bv);
        const float* wrow = wsel + row0 * CIN;

        float a8[8] = {};
        for (int c = 0; c < CIN; ++c) {
            const float xc = xt[c][lane];
#pragma unroll
            for (int u = 0; u < 8; ++u)
                a8[u] += wrow[u * CIN + c] * xc;
        }
#pragma unroll
        for (int u = 0; u < 8; ++u) {
            const int row = row0 + u;
            const float val = a8[u] + bsel[row];
            if (mi == 0)      tr[0][lane][row] = f2bf(val * scale);
            else if (mi == 1) tr[1][lane][row] = f2bf(val);
            else vb[((size_t)(b * COUT + row)) * NPIX + n0 + lane] = f2bf(val);
        }
    }
    __syncthreads();

    // write qt/kt [b][n][64] bf16, coalesced short8
    for (int idx = tid; idx < 1024; idx += 256) {
        const int m = idx >> 9, rem = idx & 511;
        const int n = rem >> 3, c8 = (rem & 7) * 8;
        unsigned short* dst = m ? kt : qt;
        *(short8*)&dst[((size_t)(b * NPIX + n0 + n)) * 64 + c8] = *(short8*)&tr[m][n][c8];
    }
}

// ---------------------------------------------------------------------------
// Kernel B: fused flash attention + output projection + residual.
// grid 512 (1-D, b = bid&7 for XCD L2 locality), block 512 = 8 waves.
// Wave w: q-group qg=w&3 (16 Q rows), j-half jh=w>>2. Per super-iter (2
// 64-wide j-tiles double-buffered): prefetch next tiles to regs (T14),
// QK^T (8 mfma), defer-max softmax (T13) with lazy per-lane l, PV (8 mfma).
// End: flash-decode merge of jh pairs via LDS, then out_c = wo*att as 64
// block MFMAs + gamma residual.  LDS pool (63 KB) with staged overlays.
// Fragment maps (m89-verified): A/B: m|n=lane&15, k=(lane>>4)*8+i;
// C/D: col=lane&15, row=(lane>>4)*4+reg.  All rows padded to 72 shorts.
// ---------------------------------------------------------------------------
#define RS 72          // row stride (shorts)
#define POOL_K   0     // [2][64][RS] u16 = 18432 B
#define POOL_V   18432 // [2][64][RS] u16 = 18432 B
#define POOL_P   36864 // [128][RS]  u16 = 18432 B  (per-wave 16-row slices)
#define POOL_Q   55296 // [64][RS]   u16 =  9216 B
#define POOL_EX  36864 // float[24][256] = 24576 B  (overlays P+Q, post-loop)
#define POOL_ATT 0     // [64][RS] u16 (overlays K, post-loop)
#define POOL_WO  18432 // [128][RS] u16 (overlays V, post-loop)

__global__ __launch_bounds__(512, 4) void flash_fused_kernel(
    const unsigned short* __restrict__ qt,
    const unsigned short* __restrict__ kt,
    const unsigned short* __restrict__ vb,
    const float* __restrict__ wo, const float* __restrict__ bo,
    const float* __restrict__ gamma, const float* __restrict__ x,
    float* __restrict__ y)
{
    __shared__ __align__(16) unsigned char pool[64512];
    unsigned short* kl = (unsigned short*)(pool + POOL_K);
    unsigned short* vl = (unsigned short*)(pool + POOL_V);
    unsigned short* pl = (unsigned short*)(pool + POOL_P);
    unsigned short* ql = (unsigned short*)(pool + POOL_Q);

    const int bid  = blockIdx.x;
    const int b    = bid & 7;             // same batch -> same XCD residue
    const int i0   = (bid >> 3) * 64;
    const int tid  = threadIdx.x;
    const int wave = tid >> 6, lane = tid & 63;
    const int l16  = lane & 15, lh = lane >> 4;
    const int qg   = wave & 3, jh = wave >> 2;

    // ---- stage Q tile (one short8 per thread) ----
    {
        const int row = tid >> 3, c8 = (tid & 7) * 8;
        *(short8*)&ql[row * RS + c8] =
            *(const short8*)&qt[((size_t)(b * NPIX + i0 + row)) * 64 + c8];
    }

    // ---- staging decode: 4 chunks/thread for 2 tiles of K and V ----
    short8 pre[4];
    const unsigned short* psrc[4];
    int pinc[4], pisK[4], pbuf[4], prow[4], pc8[4];
#pragma unroll
    for (int t = 0; t < 4; ++t) {
        const int cid = tid + t * 512;        // 0..2047
        pisK[t] = (cid >> 10) == 0;
        pbuf[t] = (cid >> 9) & 1;
        prow[t] = (cid >> 3) & 63;
        pc8[t]  = (cid & 7) * 8;
        if (pisK[t]) {  // K: [b][n][d], tile tk -> rows tk*64+row
            psrc[t] = kt + ((size_t)(b * NPIX + pbuf[t] * 64 + prow[t])) * 64 + pc8[t];
            pinc[t] = 2 * 64 * 64;            // 2 tiles of rows
        } else {        // V: [b][o][n], tile tk -> cols tk*64+c8
            psrc[t] = vb + ((size_t)(b * COUT + prow[t])) * NPIX + pbuf[t] * 64 + pc8[t];
            pinc[t] = 2 * 64;                 // 2 tiles of cols
        }
        pre[t] = *(const short8*)psrc[t];     // prologue: tiles 0,1
    }
    __syncthreads();   // Q ready

    const short8 aq0 = *(const short8*)&ql[(qg * 16 + l16) * RS + lh * 8];
    const short8 aq1 = *(const short8*)&ql[(qg * 16 + l16) * RS + 32 + lh * 8];

#pragma unroll
    for (int t = 0; t < 4; ++t) {
        unsigned short* dst = pisK[t] ? kl : vl;
        *(short8*)&dst[(pbuf[t] * 64 + prow[t]) * RS + pc8[t]] = pre[t];
    }
    __syncthreads();   // tiles 0,1 staged

    f32x4 acc[4] = {};
    float m_i[4] = {0.f, 0.f, 0.f, 0.f};
    float l_i[4] = {};

    const unsigned short* kbuf = kl + jh * (64 * RS);
    const unsigned short* vbuf = vl + jh * (64 * RS);

    for (int s = 0; s < 32; ++s) {
        // T14: issue next super-iter's global loads before compute
        if (s < 31) {
#pragma unroll
            for (int t = 0; t < 4; ++t) {
                psrc[t] += pinc[t];
                pre[t] = *(const short8*)psrc[t];
            }
        }
        // ---- QK^T ----
        f32x4 sv[4] = {};
#pragma unroll
        for (int js = 0; js < 4; ++js) {
            const short8 bk0 = *(const short8*)&kbuf[(js * 16 + l16) * RS + lh * 8];
            const short8 bk1 = *(const short8*)&kbuf[(js * 16 + l16) * RS + 32 + lh * 8];
            sv[js] = __builtin_amdgcn_mfma_f32_16x16x32_bf16(aq0, bk0, sv[js], 0, 0, 0);
            sv[js] = __builtin_amdgcn_mfma_f32_16x16x32_bf16(aq1, bk1, sv[js], 0, 0, 0);
        }
        // ---- defer-max online softmax (lazy per-lane l) ----
        float pm[4];
        bool ok = true;
#pragma unroll
        for (int r = 0; r < 4; ++r) {
            pm[r] = fmaxf(fmaxf(sv[0][r], sv[1][r]), fmaxf(sv[2][r], sv[3][r]));
            ok = ok && (pm[r] <= m_i[r] + 8.0f);
        }
        if (!__all(ok)) {   // rare slow path: full row max + rescale
#pragma unroll
            for (int r = 0; r < 4; ++r) {
                float mx = pm[r];
                mx = fmaxf(mx, __shfl_xor(mx, 1));
                mx = fmaxf(mx, __shfl_xor(mx, 2));
                mx = fmaxf(mx, __shfl_xor(mx, 4));
                mx = fmaxf(mx, __shfl_xor(mx, 8));
                const float mnew  = fmaxf(m_i[r], mx);
                const float alpha = __expf(m_i[r] - mnew);
                l_i[r] *= alpha;
#pragma unroll
                for (int os = 0; os < 4; ++os) acc[os][r] *= alpha;
                m_i[r] = mnew;
            }
        }
#pragma unroll
        for (int r = 0; r < 4; ++r) {
            const int pr = wave * 16 + lh * 4 + r;
#pragma unroll
            for (int js = 0; js < 4; ++js) {
                const float p = __expf(sv[js][r] - m_i[r]);
                l_i[r] += p;                                // lazy partial sum
                pl[pr * RS + js * 16 + l16] = f2bf(p);
            }
        }
        // ---- PV (same-wave p_lds RAW: in-order DS) ----
        const short8 ap0 = *(const short8*)&pl[(wave * 16 + l16) * RS + lh * 8];
        const short8 ap1 = *(const short8*)&pl[(wave * 16 + l16) * RS + 32 + lh * 8];
#pragma unroll
        for (int os = 0; os < 4; ++os) {
            const short8 bv0 = *(const short8*)&vbuf[(os * 16 + l16) * RS + lh * 8];
            const short8 bv1 = *(const short8*)&vbuf[(os * 16 + l16) * RS + 32 + lh * 8];
            acc[os] = __builtin_amdgcn_mfma_f32_16x16x32_bf16(ap0, bv0, acc[os], 0, 0, 0);
            acc[os] = __builtin_amdgcn_mfma_f32_16x16x32_bf16(ap1, bv1, acc[os], 0, 0, 0);
        }
        __syncthreads();                     // done reading this super-iter's tiles
        if (s < 31) {
#pragma unroll
            for (int t = 0; t < 4; ++t) {    // write prefetched tiles
                unsigned short* dst = pisK[t] ? kl : vl;
                *(short8*)&dst[(pbuf[t] * 64 + prow[t]) * RS + pc8[t]] = pre[t];
            }
            __syncthreads();                 // next tiles ready
        }
    }

    // ---- merge jh pairs (flash-decode), then fused out-projection ----
    float* ex = (float*)(pool + POOL_EX);            // [24][256]
    if (jh == 1) {
#pragma unroll
        for (int r = 0; r < 4; ++r) {
            ex[r * 256 + qg * 64 + lane]       = m_i[r];
            ex[(4 + r) * 256 + qg * 64 + lane] = l_i[r];
        }
#pragma unroll
        for (int os = 0; os < 4; ++os)
#pragma unroll
            for (int r = 0; r < 4; ++r)
                ex[(8 + os * 4 + r) * 256 + qg * 64 + lane] = acc[os][r];
    }
    __syncthreads();   // (A) exchange visible

    unsigned short* att = (unsigned short*)(pool + POOL_ATT);  // [64][RS]
    unsigned short* wol = (unsigned short*)(pool + POOL_WO);   // [128][RS]
    if (jh == 0) {
#pragma unroll
        for (int r = 0; r < 4; ++r) {
            const float mo = ex[r * 256 + qg * 64 + lane];
            const float lo = ex[(4 + r) * 256 + qg * 64 + lane];
            const float m  = fmaxf(m_i[r], mo);
            const float a0 = __expf(m_i[r] - m);
            const float a1 = __expf(mo - m);
            float lsum = l_i[r] * a0 + lo * a1;
#pragma unroll
            for (int os = 0; os < 4; ++os)
                acc[os][r] = acc[os][r] * a0 +
                             ex[(8 + os * 4 + r) * 256 + qg * 64 + lane] * a1;
            lsum += __shfl_xor(lsum, 1);
            lsum += __shfl_xor(lsum, 2);
            lsum += __shfl_xor(lsum, 4);
            lsum += __shfl_xor(lsum, 8);
            const float inv = 1.0f / lsum;
            const int i = qg * 16 + lh * 4 + r;
#pragma unroll
            for (int os = 0; os < 4; ++os)
                att[i * RS + os * 16 + l16] = f2bf(acc[os][r] * inv);
        }
    } else {
        // stage wo -> bf16 LDS [c][o]
        for (int idx = tid - 256; idx < CIN * COUT; idx += 256) {
            const int c = idx >> 6, o = idx & 63;
            wol[c * RS + o] = f2bf(wo[idx]);
        }
    }
    __syncthreads();   // (B) att + wo ready

    // out_c[c][i] = sum_o wo[c][o] * att[i][o]; wave handles c rows w*16..+15
    f32x4 acc2[4] = {};
#pragma unroll
    for (int kk = 0; kk < 2; ++kk) {
        const short8 aw = *(const short8*)&wol[(wave * 16 + l16) * RS + kk * 32 + lh * 8];
#pragma unroll
        for (int ns = 0; ns < 4; ++ns) {
            const short8 bt = *(const short8*)&att[(ns * 16 + l16) * RS + kk * 32 + lh * 8];
            acc2[ns] = __builtin_amdgcn_mfma_f32_16x16x32_bf16(aw, bt, acc2[ns], 0, 0, 0);
        }
    }
    const float g = gamma[0];
#pragma unroll
    for (int r = 0; r < 4; ++r) {
        const int c = wave * 16 + lh * 4 + r;
        const float bc = bo[c];
#pragma unroll
        for (int ns = 0; ns < 4; ++ns) {
            const size_t idx = ((size_t)(b * CIN + c)) * NPIX + i0 + ns * 16 + l16;
            y[idx] = g * (acc2[ns][r] + bc) + x[idx];
        }
    }
}

extern "C" void kernel_launch(void* const* d_in, const int* in_sizes, int n_in,
                              void* d_out, int out_size, void* d_ws, size_t ws_size,
                              hipStream_t stream)
{
    const float* x     = (const float*)d_in[0];
    const float* wq    = (const float*)d_in[1];
    const float* bq    = (const float*)d_in[2];
    const float* wk    = (const float*)d_in[3];
    const float* bk    = (const float*)d_in[4];
    const float* wv    = (const float*)d_in[5];
    const float* bv    = (const float*)d_in[6];
    const float* wo    = (const float*)d_in[7];
    const float* bo    = (const float*)d_in[8];
    const float* gamma = (const float*)d_in[9];
    float* out = (float*)d_out;

    const size_t plane = (size_t)B_ * NPIX * 64;     // 2M elems
    unsigned short* qt = (unsigned short*)d_ws;      // 4 MB
    unsigned short* kt = qt + plane;                 // 4 MB
    unsigned short* vb = kt + plane;                 // 4 MB

    qkv_proj_kernel<<<dim3(NPIX / 64, B_), 256, 0, stream>>>(
        x, wq, bq, wk, bk, wv, bv, qt, kt, vb);
    flash_fused_kernel<<<dim3(512), 512, 0, stream>>>(
        qt, kt, vb, wo, bo, gamma, x, out);
}

// Round 9
// 174.858 us; speedup vs baseline: 4.0006x; 1.4351x over previous
//
#include <hip/hip_runtime.h>
#include <hip/hip_bf16.h>

#define B_   8
#define CIN  128
#define COUT 64
#define NPIX 4096

typedef __attribute__((ext_vector_type(8))) short short8;
typedef __attribute__((ext_vector_type(4))) short short4_t;
typedef __attribute__((ext_vector_type(4))) float f32x4;

// f32 -> bf16 round-to-nearest-even
__device__ __forceinline__ unsigned short f2bf(float f) {
    union { float f; unsigned int u; } x; x.f = f;
    return (unsigned short)((x.u + 0x7FFF + ((x.u >> 16) & 1)) >> 16);
}

// ---------------------------------------------------------------------------
// Kernel A0: weight pre-convert. wb[192][128] bf16 = [wq*scale; wk; wv].
// One-shot, ~2 us; makes A-fragments loadable directly from global (L2-hot).
// ---------------------------------------------------------------------------
__global__ __launch_bounds__(256) void w2bf_kernel(
    const float* __restrict__ wq, const float* __restrict__ wk,
    const float* __restrict__ wv, unsigned short* __restrict__ wb)
{
    const int idx = blockIdx.x * 256 + threadIdx.x;   // 0..24575
    if (idx >= 192 * CIN) return;
    const int row = idx >> 7, c = idx & 127;
    float v;
    if (row < 64)       v = wq[row * CIN + c] * 0.08838834764831845f; // fold 1/sqrt(CIN)
    else if (row < 128) v = wk[(row - 64) * CIN + c];
    else                v = wv[(row - 128) * CIN + c];
    wb[idx] = f2bf(v);
}

// ---------------------------------------------------------------------------
// Kernel A: QKV projection as MFMA GEMM.
// grid (NPIX/64, B), block 512 = 8 waves. Wave: nt=wave&3 (16-pixel n-tile),
// mh=wave>>2 (6 of 12 m-tiles). Per wave: 4 B-frags (x) from LDS, 6x4 A-frags
// (weights) from global bf16, 24 MFMA. Epilogue: v -> global direct;
// q/k -> LDS transpose (overlays xb) -> coalesced short8 stores.
// Fragment maps (m89-verified): A/B: m|n=lane&15, k=(lane>>4)*8+i;
// C/D: col=lane&15 (n), row=(lane>>4)*4+reg (o).
// ---------------------------------------------------------------------------
#define XRS 136   // xb row stride in shorts (272B, 16B-aligned)
#define TRS 72    // tr row stride in shorts (144B, 16B-aligned)

__global__ __launch_bounds__(512) void qkv_mfma_kernel(
    const float* __restrict__ x, const unsigned short* __restrict__ wb,
    const float* __restrict__ bq, const float* __restrict__ bk,
    const float* __restrict__ bv,
    unsigned short* __restrict__ qt, unsigned short* __restrict__ kt,
    unsigned short* __restrict__ vb)
{
    __shared__ __align__(16) unsigned char pool[18432]; // max(xb 17408B, tr 18432B)
    unsigned short* xb  = (unsigned short*)pool;        // [64 n][XRS]
    unsigned short* trq = (unsigned short*)pool;        // [64 n][TRS] (overlay, post-MFMA)
    unsigned short* trk = trq + 64 * TRS;

    const int n0   = blockIdx.x * 64;
    const int b    = blockIdx.y;
    const int tid  = threadIdx.x;
    const int wave = tid >> 6, lane = tid & 63;
    const int l16  = lane & 15, lh = lane >> 4;
    const int nt   = wave & 3, mh = wave >> 2;
    const float scale = 0.08838834764831845f;

    // stage x tile -> xb[n][c] bf16 (global reads coalesced 256B/row)
    for (int i = tid; i < CIN * 64; i += 512) {
        const int c = i >> 6, n = i & 63;
        xb[n * XRS + c] = f2bf(x[((size_t)(b * CIN + c)) * NPIX + n0 + n]);
    }
    __syncthreads();

    // B-fragments for this wave's n-tile (k-contiguous in c)
    const int n_ = nt * 16 + l16;
    short8 bx[4];
#pragma unroll
    for (int kk = 0; kk < 4; ++kk)
        bx[kk] = *(const short8*)&xb[n_ * XRS + kk * 32 + lh * 8];
    __syncthreads();   // all waves done with xb before tr overlay writes

    // MFMA: 6 m-tiles x 4 k-steps; A-frags straight from global bf16 (L2-hot)
    f32x4 acc[6] = {};
#pragma unroll
    for (int m6 = 0; m6 < 6; ++m6) {
        const int mt = mh * 6 + m6;
        const unsigned short* wrow = wb + (size_t)(mt * 16 + l16) * CIN;
#pragma unroll
        for (int kk = 0; kk < 4; ++kk) {
            const short8 aw = *(const short8*)&wrow[kk * 32 + lh * 8];
            acc[m6] = __builtin_amdgcn_mfma_f32_16x16x32_bf16(aw, bx[kk], acc[m6], 0, 0, 0);
        }
    }

    // epilogue: q (mt 0-3) / k (mt 4-7) -> LDS transpose; v (mt 8-11) -> global
#pragma unroll
    for (int m6 = 0; m6 < 6; ++m6) {
        const int mt = mh * 6 + m6;
        const int o0 = (mt & 3) * 16 + lh * 4;   // o within 64-row group (q/k)
        if (mt < 4) {            // q: bias bq*scale (scale folded into weights too)
            short4_t pk;
#pragma unroll
            for (int r = 0; r < 4; ++r) pk[r] = (short)f2bf(acc[m6][r] + bq[o0 + r] * scale);
            *(short4_t*)&trq[n_ * TRS + o0] = pk;
        } else if (mt < 8) {     // k
            short4_t pk;
#pragma unroll
            for (int r = 0; r < 4; ++r) pk[r] = (short)f2bf(acc[m6][r] + bk[o0 + r]);
            *(short4_t*)&trk[n_ * TRS + o0] = pk;
        } else {                 // v: [o][n] direct, 16 lanes = 32B contiguous
            const int ov = (mt - 8) * 16 + lh * 4;
#pragma unroll
            for (int r = 0; r < 4; ++r)
                vb[((size_t)(b * COUT + ov + r)) * NPIX + n0 + n_] = f2bf(acc[m6][r] + bv[ov + r]);
        }
    }
    __syncthreads();   // tr complete

    // coalesced copy-out: qt/kt [b][n][64] bf16
    for (int idx = tid; idx < 1024; idx += 512) {
        const int m = idx >> 9, rem = idx & 511;
        const int row = rem >> 3, c8 = (rem & 7) * 8;
        const unsigned short* src = m ? &trk[row * TRS + c8] : &trq[row * TRS + c8];
        unsigned short* dst = m ? kt : qt;
        *(short8*)&dst[((size_t)(b * NPIX + n0 + row)) * 64 + c8] = *(const short8*)src;
    }
}

// ---------------------------------------------------------------------------
// Kernel B: fused flash attention + output projection + residual. (UNCHANGED
// from R5 — isolating the qkv fix; flash counters land in next round's top-5.)
// ---------------------------------------------------------------------------
#define RS 72          // row stride (shorts)
#define POOL_K   0     // [2][64][RS] u16 = 18432 B
#define POOL_V   18432 // [2][64][RS] u16 = 18432 B
#define POOL_P   36864 // [128][RS]  u16 = 18432 B  (per-wave 16-row slices)
#define POOL_Q   55296 // [64][RS]   u16 =  9216 B
#define POOL_EX  36864 // float[24][256] = 24576 B  (overlays P+Q, post-loop)
#define POOL_ATT 0     // [64][RS] u16 (overlays K, post-loop)
#define POOL_WO  18432 // [128][RS] u16 (overlays V, post-loop)

__global__ __launch_bounds__(512, 4) void flash_fused_kernel(
    const unsigned short* __restrict__ qt,
    const unsigned short* __restrict__ kt,
    const unsigned short* __restrict__ vb,
    const float* __restrict__ wo, const float* __restrict__ bo,
    const float* __restrict__ gamma, const float* __restrict__ x,
    float* __restrict__ y)
{
    __shared__ __align__(16) unsigned char pool[64512];
    unsigned short* kl = (unsigned short*)(pool + POOL_K);
    unsigned short* vl = (unsigned short*)(pool + POOL_V);
    unsigned short* pl = (unsigned short*)(pool + POOL_P);
    unsigned short* ql = (unsigned short*)(pool + POOL_Q);

    const int bid  = blockIdx.x;
    const int b    = bid & 7;             // same batch -> same XCD residue
    const int i0   = (bid >> 3) * 64;
    const int tid  = threadIdx.x;
    const int wave = tid >> 6, lane = tid & 63;
    const int l16  = lane & 15, lh = lane >> 4;
    const int qg   = wave & 3, jh = wave >> 2;

    // ---- stage Q tile (one short8 per thread) ----
    {
        const int row = tid >> 3, c8 = (tid & 7) * 8;
        *(short8*)&ql[row * RS + c8] =
            *(const short8*)&qt[((size_t)(b * NPIX + i0 + row)) * 64 + c8];
    }

    // ---- staging decode: 4 chunks/thread for 2 tiles of K and V ----
    short8 pre[4];
    const unsigned short* psrc[4];
    int pinc[4], pisK[4], pbuf[4], prow[4], pc8[4];
#pragma unroll
    for (int t = 0; t < 4; ++t) {
        const int cid = tid + t * 512;        // 0..2047
        pisK[t] = (cid >> 10) == 0;
        pbuf[t] = (cid >> 9) & 1;
        prow[t] = (cid >> 3) & 63;
        pc8[t]  = (cid & 7) * 8;
        if (pisK[t]) {  // K: [b][n][d], tile tk -> rows tk*64+row
            psrc[t] = kt + ((size_t)(b * NPIX + pbuf[t] * 64 + prow[t])) * 64 + pc8[t];
            pinc[t] = 2 * 64 * 64;            // 2 tiles of rows
        } else {        // V: [b][o][n], tile tk -> cols tk*64+c8
            psrc[t] = vb + ((size_t)(b * COUT + prow[t])) * NPIX + pbuf[t] * 64 + pc8[t];
            pinc[t] = 2 * 64;                 // 2 tiles of cols
        }
        pre[t] = *(const short8*)psrc[t];     // prologue: tiles 0,1
    }
    __syncthreads();   // Q ready

    const short8 aq0 = *(const short8*)&ql[(qg * 16 + l16) * RS + lh * 8];
    const short8 aq1 = *(const short8*)&ql[(qg * 16 + l16) * RS + 32 + lh * 8];

#pragma unroll
    for (int t = 0; t < 4; ++t) {
        unsigned short* dst = pisK[t] ? kl : vl;
        *(short8*)&dst[(pbuf[t] * 64 + prow[t]) * RS + pc8[t]] = pre[t];
    }
    __syncthreads();   // tiles 0,1 staged

    f32x4 acc[4] = {};
    float m_i[4] = {0.f, 0.f, 0.f, 0.f};
    float l_i[4] = {};

    const unsigned short* kbuf = kl + jh * (64 * RS);
    const unsigned short* vbuf = vl + jh * (64 * RS);

    for (int s = 0; s < 32; ++s) {
        // T14: issue next super-iter's global loads before compute
        if (s < 31) {
#pragma unroll
            for (int t = 0; t < 4; ++t) {
                psrc[t] += pinc[t];
                pre[t] = *(const short8*)psrc[t];
            }
        }
        // ---- QK^T ----
        f32x4 sv[4] = {};
#pragma unroll
        for (int js = 0; js < 4; ++js) {
            const short8 bk0 = *(const short8*)&kbuf[(js * 16 + l16) * RS + lh * 8];
            const short8 bk1 = *(const short8*)&kbuf[(js * 16 + l16) * RS + 32 + lh * 8];
            sv[js] = __builtin_amdgcn_mfma_f32_16x16x32_bf16(aq0, bk0, sv[js], 0, 0, 0);
            sv[js] = __builtin_amdgcn_mfma_f32_16x16x32_bf16(aq1, bk1, sv[js], 0, 0, 0);
        }
        // ---- defer-max online softmax (lazy per-lane l) ----
        float pm[4];
        bool ok = true;
#pragma unroll
        for (int r = 0; r < 4; ++r) {
            pm[r] = fmaxf(fmaxf(sv[0][r], sv[1][r]), fmaxf(sv[2][r], sv[3][r]));
            ok = ok && (pm[r] <= m_i[r] + 8.0f);
        }
        if (!__all(ok)) {   // rare slow path: full row max + rescale
#pragma unroll
            for (int r = 0; r < 4; ++r) {
                float mx = pm[r];
                mx = fmaxf(mx, __shfl_xor(mx, 1));
                mx = fmaxf(mx, __shfl_xor(mx, 2));
                mx = fmaxf(mx, __shfl_xor(mx, 4));
                mx = fmaxf(mx, __shfl_xor(mx, 8));
                const float mnew  = fmaxf(m_i[r], mx);
                const float alpha = __expf(m_i[r] - mnew);
                l_i[r] *= alpha;
#pragma unroll
                for (int os = 0; os < 4; ++os) acc[os][r] *= alpha;
                m_i[r] = mnew;
            }
        }
#pragma unroll
        for (int r = 0; r < 4; ++r) {
            const int pr = wave * 16 + lh * 4 + r;
#pragma unroll
            for (int js = 0; js < 4; ++js) {
                const float p = __expf(sv[js][r] - m_i[r]);
                l_i[r] += p;                                // lazy partial sum
                pl[pr * RS + js * 16 + l16] = f2bf(p);
            }
        }
        // ---- PV (same-wave p_lds RAW: in-order DS) ----
        const short8 ap0 = *(const short8*)&pl[(wave * 16 + l16) * RS + lh * 8];
        const short8 ap1 = *(const short8*)&pl[(wave * 16 + l16) * RS + 32 + lh * 8];
#pragma unroll
        for (int os = 0; os < 4; ++os) {
            const short8 bv0 = *(const short8*)&vbuf[(os * 16 + l16) * RS + lh * 8];
            const short8 bv1 = *(const short8*)&vbuf[(os * 16 + l16) * RS + 32 + lh * 8];
            acc[os] = __builtin_amdgcn_mfma_f32_16x16x32_bf16(ap0, bv0, acc[os], 0, 0, 0);
            acc[os] = __builtin_amdgcn_mfma_f32_16x16x32_bf16(ap1, bv1, acc[os], 0, 0, 0);
        }
        __syncthreads();                     // done reading this super-iter's tiles
        if (s < 31) {
#pragma unroll
            for (int t = 0; t < 4; ++t) {    // write prefetched tiles
                unsigned short* dst = pisK[t] ? kl : vl;
                *(short8*)&dst[(pbuf[t] * 64 + prow[t]) * RS + pc8[t]] = pre[t];
            }
            __syncthreads();                 // next tiles ready
        }
    }

    // ---- merge jh pairs (flash-decode), then fused out-projection ----
    float* ex = (float*)(pool + POOL_EX);            // [24][256]
    if (jh == 1) {
#pragma unroll
        for (int r = 0; r < 4; ++r) {
            ex[r * 256 + qg * 64 + lane]       = m_i[r];
            ex[(4 + r) * 256 + qg * 64 + lane] = l_i[r];
        }
#pragma unroll
        for (int os = 0; os < 4; ++os)
#pragma unroll
            for (int r = 0; r < 4; ++r)
                ex[(8 + os * 4 + r) * 256 + qg * 64 + lane] = acc[os][r];
    }
    __syncthreads();   // (A) exchange visible

    unsigned short* att = (unsigned short*)(pool + POOL_ATT);  // [64][RS]
    unsigned short* wol = (unsigned short*)(pool + POOL_WO);   // [128][RS]
    if (jh == 0) {
#pragma unroll
        for (int r = 0; r < 4; ++r) {
            const float mo = ex[r * 256 + qg * 64 + lane];
            const float lo = ex[(4 + r) * 256 + qg * 64 + lane];
            const float m  = fmaxf(m_i[r], mo);
            const float a0 = __expf(m_i[r] - m);
            const float a1 = __expf(mo - m);
            float lsum = l_i[r] * a0 + lo * a1;
#pragma unroll
            for (int os = 0; os < 4; ++os)
                acc[os][r] = acc[os][r] * a0 +
                             ex[(8 + os * 4 + r) * 256 + qg * 64 + lane] * a1;
            lsum += __shfl_xor(lsum, 1);
            lsum += __shfl_xor(lsum, 2);
            lsum += __shfl_xor(lsum, 4);
            lsum += __shfl_xor(lsum, 8);
            const float inv = 1.0f / lsum;
            const int i = qg * 16 + lh * 4 + r;
#pragma unroll
            for (int os = 0; os < 4; ++os)
                att[i * RS + os * 16 + l16] = f2bf(acc[os][r] * inv);
        }
    } else {
        // stage wo -> bf16 LDS [c][o]
        for (int idx = tid - 256; idx < CIN * COUT; idx += 256) {
            const int c = idx >> 6, o = idx & 63;
            wol[c * RS + o] = f2bf(wo[idx]);
        }
    }
    __syncthreads();   // (B) att + wo ready

    // out_c[c][i] = sum_o wo[c][o] * att[i][o]; wave handles c rows w*16..+15
    f32x4 acc2[4] = {};
#pragma unroll
    for (int kk = 0; kk < 2; ++kk) {
        const short8 aw = *(const short8*)&wol[(wave * 16 + l16) * RS + kk * 32 + lh * 8];
#pragma unroll
        for (int ns = 0; ns < 4; ++ns) {
            const short8 bt = *(const short8*)&att[(ns * 16 + l16) * RS + kk * 32 + lh * 8];
            acc2[ns] = __builtin_amdgcn_mfma_f32_16x16x32_bf16(aw, bt, acc2[ns], 0, 0, 0);
        }
    }
    const float g = gamma[0];
#pragma unroll
    for (int r = 0; r < 4; ++r) {
        const int c = wave * 16 + lh * 4 + r;
        const float bc = bo[c];
#pragma unroll
        for (int ns = 0; ns < 4; ++ns) {
            const size_t idx = ((size_t)(b * CIN + c)) * NPIX + i0 + ns * 16 + l16;
            y[idx] = g * (acc2[ns][r] + bc) + x[idx];
        }
    }
}

extern "C" void kernel_launch(void* const* d_in, const int* in_sizes, int n_in,
                              void* d_out, int out_size, void* d_ws, size_t ws_size,
                              hipStream_t stream)
{
    const float* x     = (const float*)d_in[0];
    const float* wq    = (const float*)d_in[1];
    const float* bq    = (const float*)d_in[2];
    const float* wk    = (const float*)d_in[3];
    const float* bk    = (const float*)d_in[4];
    const float* wv    = (const float*)d_in[5];
    const float* bv    = (const float*)d_in[6];
    const float* wo    = (const float*)d_in[7];
    const float* bo    = (const float*)d_in[8];
    const float* gamma = (const float*)d_in[9];
    float* out = (float*)d_out;

    const size_t plane = (size_t)B_ * NPIX * 64;     // 2M elems
    unsigned short* qt = (unsigned short*)d_ws;      // 4 MB
    unsigned short* kt = qt + plane;                 // 4 MB
    unsigned short* vb = kt + plane;                 // 4 MB
    unsigned short* wb = vb + plane;                 // 48 KB (bf16 weights)

    w2bf_kernel<<<dim3(96), 256, 0, stream>>>(wq, wk, wv, wb);
    qkv_mfma_kernel<<<dim3(NPIX / 64, B_), 512, 0, stream>>>(
        x, wb, bq, bk, bv, qt, kt, vb);
    flash_fused_kernel<<<dim3(512), 512, 0, stream>>>(
        qt, kt, vb, wo, bo, gamma, x, out);
}

// Round 10
// 165.003 us; speedup vs baseline: 4.2396x; 1.0597x over previous
//
#include <hip/hip_runtime.h>
#include <hip/hip_bf16.h>

#define B_   8
#define CIN  128
#define COUT 64
#define NPIX 4096

typedef __attribute__((ext_vector_type(8))) short short8;
typedef __attribute__((ext_vector_type(4))) short short4_t;
typedef __attribute__((ext_vector_type(4))) float f32x4;

// f32 -> bf16 RNE via compiler intrinsic (emits v_cvt_pk_bf16_f32; m240:
// manual bit-ops / hand-asm both lose to the compiler here)
__device__ __forceinline__ unsigned short f2bf(float f) {
    union { __hip_bfloat16 b; unsigned short u; } c;
    c.b = __float2bfloat16(f);
    return c.u;
}

// ---------------------------------------------------------------------------
// Kernel A0: weight pre-convert. wb[192][128] bf16 = [wq*scale; wk; wv].
// ---------------------------------------------------------------------------
__global__ __launch_bounds__(256) void w2bf_kernel(
    const float* __restrict__ wq, const float* __restrict__ wk,
    const float* __restrict__ wv, unsigned short* __restrict__ wb)
{
    const int idx = blockIdx.x * 256 + threadIdx.x;   // 0..24575
    if (idx >= 192 * CIN) return;
    const int row = idx >> 7, c = idx & 127;
    float v;
    if (row < 64)       v = wq[row * CIN + c] * 0.08838834764831845f; // fold 1/sqrt(CIN)
    else if (row < 128) v = wk[(row - 64) * CIN + c];
    else                v = wv[(row - 128) * CIN + c];
    wb[idx] = f2bf(v);
}

// ---------------------------------------------------------------------------
// Kernel A: QKV projection as MFMA GEMM.  v3: 32-pixel blocks (2x occupancy:
// 1024 blocks, 16 waves/CU), float4 x-loads (4x fewer staging instrs).
// grid (NPIX/32, B), block 256 = 4 waves. Wave: nt=w&1 (16-pixel n-tile),
// mh=w>>1 (6 of 12 m-tiles). B-frags (x) from LDS transpose; A-frags
// (weights) from global bf16 (L2-hot); 24 MFMA/wave.
// Fragment maps (m89-verified): A/B: m|n=lane&15, k=(lane>>4)*8+i;
// C/D: col=lane&15 (n), row=(lane>>4)*4+reg (o).
// ---------------------------------------------------------------------------
#define XRS 136   // xb row stride in shorts (272B, 16B-aligned)
#define TRS 72    // tr row stride in shorts (144B, 16B-aligned)

__global__ __launch_bounds__(256) void qkv_mfma_kernel(
    const float* __restrict__ x, const unsigned short* __restrict__ wb,
    const float* __restrict__ bq, const float* __restrict__ bk,
    const float* __restrict__ bv,
    unsigned short* __restrict__ qt, unsigned short* __restrict__ kt,
    unsigned short* __restrict__ vb)
{
    __shared__ __align__(16) unsigned char pool[9216];  // xb 8704B / tr 9216B overlay
    unsigned short* xb  = (unsigned short*)pool;        // [32 n][XRS]
    unsigned short* trq = (unsigned short*)pool;        // [32 n][TRS] (post-MFMA overlay)
    unsigned short* trk = trq + 32 * TRS;

    const int n0   = blockIdx.x * 32;
    const int b    = blockIdx.y;
    const int tid  = threadIdx.x;
    const int wave = tid >> 6, lane = tid & 63;
    const int l16  = lane & 15, lh = lane >> 4;
    const int nt   = wave & 1, mh = wave >> 1;
    const float scale = 0.08838834764831845f;

    // stage x tile -> xb[n][c] bf16; float4 global loads (16B/lane)
    for (int i = tid; i < 1024; i += 256) {
        const int c = i >> 3, n4 = (i & 7) * 4;
        const float4 v4 = *(const float4*)&x[((size_t)(b * CIN + c)) * NPIX + n0 + n4];
        xb[(n4 + 0) * XRS + c] = f2bf(v4.x);
        xb[(n4 + 1) * XRS + c] = f2bf(v4.y);
        xb[(n4 + 2) * XRS + c] = f2bf(v4.z);
        xb[(n4 + 3) * XRS + c] = f2bf(v4.w);
    }
    __syncthreads();

    const int n_ = nt * 16 + l16;
    short8 bx[4];
#pragma unroll
    for (int kk = 0; kk < 4; ++kk)
        bx[kk] = *(const short8*)&xb[n_ * XRS + kk * 32 + lh * 8];
    __syncthreads();   // all waves done with xb before tr overlay writes

    f32x4 acc[6] = {};
#pragma unroll
    for (int m6 = 0; m6 < 6; ++m6) {
        const int mt = mh * 6 + m6;
        const unsigned short* wrow = wb + (size_t)(mt * 16 + l16) * CIN;
#pragma unroll
        for (int kk = 0; kk < 4; ++kk) {
            const short8 aw = *(const short8*)&wrow[kk * 32 + lh * 8];
            acc[m6] = __builtin_amdgcn_mfma_f32_16x16x32_bf16(aw, bx[kk], acc[m6], 0, 0, 0);
        }
    }

    // epilogue: q (mt 0-3) / k (mt 4-7) -> LDS transpose; v (mt 8-11) -> global
#pragma unroll
    for (int m6 = 0; m6 < 6; ++m6) {
        const int mt = mh * 6 + m6;
        const int o0 = (mt & 3) * 16 + lh * 4;
        if (mt < 4) {
            short4_t pk;
#pragma unroll
            for (int r = 0; r < 4; ++r) pk[r] = (short)f2bf(acc[m6][r] + bq[o0 + r] * scale);
            *(short4_t*)&trq[n_ * TRS + o0] = pk;
        } else if (mt < 8) {
            short4_t pk;
#pragma unroll
            for (int r = 0; r < 4; ++r) pk[r] = (short)f2bf(acc[m6][r] + bk[o0 + r]);
            *(short4_t*)&trk[n_ * TRS + o0] = pk;
        } else {
            const int ov = (mt - 8) * 16 + lh * 4;
#pragma unroll
            for (int r = 0; r < 4; ++r)
                vb[((size_t)(b * COUT + ov + r)) * NPIX + n0 + n_] = f2bf(acc[m6][r] + bv[ov + r]);
        }
    }
    __syncthreads();   // tr complete

    // coalesced copy-out: qt/kt [b][n][64] bf16
    for (int idx = tid; idx < 512; idx += 256) {
        const int m = idx >> 8, rem = idx & 255;
        const int row = rem >> 3, c8 = (rem & 7) * 8;
        const unsigned short* src = m ? &trk[row * TRS + c8] : &trq[row * TRS + c8];
        unsigned short* dst = m ? kt : qt;
        *(short8*)&dst[((size_t)(b * NPIX + n0 + row)) * 64 + c8] = *(const short8*)src;
    }
}

// ---------------------------------------------------------------------------
// Kernel B: fused flash attention + output projection + residual.
// v2: SWAPPED QK^T (mfma(K,Q) -> S^T: col=l16=i, row=lh*4+r=j).  Same LDS
// read addresses as v1, but: P-write = 4x ds_write_b64 (conflict-free, was
// 16x u16 4-way); fast-path softmax has ZERO shuffles (per-lane threshold,
// m/l scalars in i=l16 space); rare slow path / merge cross to row space
// via ds_bpermute.  PV and fused out-proj unchanged.
// ---------------------------------------------------------------------------
#define RS 72          // row stride (shorts)
#define POOL_K   0     // [2][64][RS] u16 = 18432 B
#define POOL_V   18432 // [2][64][RS] u16 = 18432 B
#define POOL_P   36864 // [128][RS]  u16 = 18432 B  (per-wave 16-row slices)
#define POOL_Q   55296 // [64][RS]   u16 =  9216 B
#define POOL_EXA 36864 // float[16][256] = 16384 B (acc exchange; overlays P, post-loop)
#define POOL_EXM 53248 // float[64] (row max)
#define POOL_EXL 53504 // float[64] (row sum)
#define POOL_ATT 0     // [64][RS] u16 (overlays K, post-loop)
#define POOL_WO  18432 // [128][RS] u16 (overlays V, post-loop)

__global__ __launch_bounds__(512, 4) void flash_fused_kernel(
    const unsigned short* __restrict__ qt,
    const unsigned short* __restrict__ kt,
    const unsigned short* __restrict__ vb,
    const float* __restrict__ wo, const float* __restrict__ bo,
    const float* __restrict__ gamma, const float* __restrict__ x,
    float* __restrict__ y)
{
    __shared__ __align__(16) unsigned char pool[64512];
    unsigned short* kl = (unsigned short*)(pool + POOL_K);
    unsigned short* vl = (unsigned short*)(pool + POOL_V);
    unsigned short* pl = (unsigned short*)(pool + POOL_P);
    unsigned short* ql = (unsigned short*)(pool + POOL_Q);

    const int bid  = blockIdx.x;
    const int b    = bid & 7;             // same batch -> same XCD residue
    const int i0   = (bid >> 3) * 64;
    const int tid  = threadIdx.x;
    const int wave = tid >> 6, lane = tid & 63;
    const int l16  = lane & 15, lh = lane >> 4;
    const int qg   = wave & 3, jh = wave >> 2;

    // ---- stage Q tile ----
    {
        const int row = tid >> 3, c8 = (tid & 7) * 8;
        *(short8*)&ql[row * RS + c8] =
            *(const short8*)&qt[((size_t)(b * NPIX + i0 + row)) * 64 + c8];
    }

    // ---- staging decode: 4 chunks/thread for 2 tiles of K and V ----
    short8 pre[4];
    const unsigned short* psrc[4];
    int pinc[4], pisK[4], pbuf[4], prw[4], pc8[4];
#pragma unroll
    for (int t = 0; t < 4; ++t) {
        const int cid = tid + t * 512;        // 0..2047
        pisK[t] = (cid >> 10) == 0;
        pbuf[t] = (cid >> 9) & 1;
        prw[t]  = (cid >> 3) & 63;
        pc8[t]  = (cid & 7) * 8;
        if (pisK[t]) {
            psrc[t] = kt + ((size_t)(b * NPIX + pbuf[t] * 64 + prw[t])) * 64 + pc8[t];
            pinc[t] = 2 * 64 * 64;
        } else {
            psrc[t] = vb + ((size_t)(b * COUT + prw[t])) * NPIX + pbuf[t] * 64 + pc8[t];
            pinc[t] = 2 * 64;
        }
        pre[t] = *(const short8*)psrc[t];     // prologue: tiles 0,1
    }
    __syncthreads();   // Q ready

    const short8 aq0 = *(const short8*)&ql[(qg * 16 + l16) * RS + lh * 8];
    const short8 aq1 = *(const short8*)&ql[(qg * 16 + l16) * RS + 32 + lh * 8];

#pragma unroll
    for (int t = 0; t < 4; ++t) {
        unsigned short* dst = pisK[t] ? kl : vl;
        *(short8*)&dst[(pbuf[t] * 64 + prw[t]) * RS + pc8[t]] = pre[t];
    }
    __syncthreads();   // tiles 0,1 staged

    f32x4 acc[4] = {};
    float m_s = 0.f, l_s = 0.f;   // per-lane state for q-row i = qg*16 + l16

    const unsigned short* kbuf = kl + jh * (64 * RS);
    const unsigned short* vbuf = vl + jh * (64 * RS);
    const int prow = wave * 16 + l16;

    for (int s = 0; s < 32; ++s) {
        // T14: issue next super-iter's global loads before compute
        if (s < 31) {
#pragma unroll
            for (int t = 0; t < 4; ++t) {
                psrc[t] += pinc[t];
                pre[t] = *(const short8*)psrc[t];
            }
        }
        // ---- QK^T swapped: sv[js][r] = S[i = qg*16+l16][j = js*16+lh*4+r] ----
        f32x4 sv[4] = {};
#pragma unroll
        for (int js = 0; js < 4; ++js) {
            const short8 bk0 = *(const short8*)&kbuf[(js * 16 + l16) * RS + lh * 8];
            const short8 bk1 = *(const short8*)&kbuf[(js * 16 + l16) * RS + 32 + lh * 8];
            sv[js] = __builtin_amdgcn_mfma_f32_16x16x32_bf16(bk0, aq0, sv[js], 0, 0, 0);
            sv[js] = __builtin_amdgcn_mfma_f32_16x16x32_bf16(bk1, aq1, sv[js], 0, 0, 0);
        }
        // ---- defer-max softmax: per-lane threshold, no shuffles fast-path ----
        float pm = sv[0][0];
#pragma unroll
        for (int js = 0; js < 4; ++js)
#pragma unroll
            for (int r = 0; r < 4; ++r) pm = fmaxf(pm, sv[js][r]);
        if (!__all(pm <= m_s + 8.0f)) {      // rare slow path (wave-uniform)
            float mrow = pm;
            mrow = fmaxf(mrow, __shfl_xor(mrow, 16));
            mrow = fmaxf(mrow, __shfl_xor(mrow, 32));
            const float mnew  = fmaxf(m_s, mrow);
            const float alpha = __expf(m_s - mnew);
            l_s *= alpha;
#pragma unroll
            for (int r = 0; r < 4; ++r) {
                const float ar = __shfl(alpha, lh * 4 + r);   // i=l16 -> row space
#pragma unroll
                for (int os = 0; os < 4; ++os) acc[os][r] *= ar;
            }
            m_s = mnew;
        }
#pragma unroll
        for (int js = 0; js < 4; ++js) {
            const float p0 = __expf(sv[js][0] - m_s);
            const float p1 = __expf(sv[js][1] - m_s);
            const float p2 = __expf(sv[js][2] - m_s);
            const float p3 = __expf(sv[js][3] - m_s);
            l_s += (p0 + p1) + (p2 + p3);
            short4_t pk;
            pk[0] = (short)f2bf(p0); pk[1] = (short)f2bf(p1);
            pk[2] = (short)f2bf(p2); pk[3] = (short)f2bf(p3);
            *(short4_t*)&pl[prow * RS + js * 16 + lh * 4] = pk;   // b64, conflict-free
        }
        // ---- PV (same-wave p_lds RAW: in-order DS); operands unchanged ----
        const short8 ap0 = *(const short8*)&pl[prow * RS + lh * 8];
        const short8 ap1 = *(const short8*)&pl[prow * RS + 32 + lh * 8];
#pragma unroll
        for (int os = 0; os < 4; ++os) {
            const short8 bv0 = *(const short8*)&vbuf[(os * 16 + l16) * RS + lh * 8];
            const short8 bv1 = *(const short8*)&vbuf[(os * 16 + l16) * RS + 32 + lh * 8];
            acc[os] = __builtin_amdgcn_mfma_f32_16x16x32_bf16(ap0, bv0, acc[os], 0, 0, 0);
            acc[os] = __builtin_amdgcn_mfma_f32_16x16x32_bf16(ap1, bv1, acc[os], 0, 0, 0);
        }
        __syncthreads();
        if (s < 31) {
#pragma unroll
            for (int t = 0; t < 4; ++t) {
                unsigned short* dst = pisK[t] ? kl : vl;
                *(short8*)&dst[(pbuf[t] * 64 + prw[t]) * RS + pc8[t]] = pre[t];
            }
            __syncthreads();
        }
    }

    // complete row sums over the 4 lh replicas (m_s already row-consistent)
    l_s += __shfl_xor(l_s, 16);
    l_s += __shfl_xor(l_s, 32);

    // ---- merge jh pairs, then fused out-projection ----
    float* exa = (float*)(pool + POOL_EXA);
    float* exm = (float*)(pool + POOL_EXM);
    float* exl = (float*)(pool + POOL_EXL);
    if (jh == 1) {
        if (lh == 0) { exm[qg * 16 + l16] = m_s; exl[qg * 16 + l16] = l_s; }
#pragma unroll
        for (int os = 0; os < 4; ++os)
#pragma unroll
            for (int r = 0; r < 4; ++r)
                exa[(os * 4 + r) * 256 + qg * 64 + lane] = acc[os][r];
    }
    __syncthreads();   // (A)

    unsigned short* att = (unsigned short*)(pool + POOL_ATT);  // [64][RS]
    unsigned short* wol = (unsigned short*)(pool + POOL_WO);   // [128][RS]
    if (jh == 0) {
        const float mo = exm[qg * 16 + l16];
        const float lo = exl[qg * 16 + l16];
        const float m  = fmaxf(m_s, mo);
        const float a0 = __expf(m_s - m);
        const float a1 = __expf(mo - m);
        const float inv = 1.0f / (l_s * a0 + lo * a1);
#pragma unroll
        for (int r = 0; r < 4; ++r) {
            const float a0r = __shfl(a0, lh * 4 + r);
            const float a1r = __shfl(a1, lh * 4 + r);
            const float ivr = __shfl(inv, lh * 4 + r);
            const int i = qg * 16 + lh * 4 + r;
#pragma unroll
            for (int os = 0; os < 4; ++os) {
                const float v = (acc[os][r] * a0r +
                                 exa[(os * 4 + r) * 256 + qg * 64 + lane] * a1r) * ivr;
                att[i * RS + os * 16 + l16] = f2bf(v);
            }
        }
    } else {
        for (int idx = tid - 256; idx < CIN * COUT; idx += 256) {
            const int c = idx >> 6, o = idx & 63;
            wol[c * RS + o] = f2bf(wo[idx]);
        }
    }
    __syncthreads();   // (B) att + wo ready

    // out_c[c][i] = sum_o wo[c][o] * att[i][o]; wave handles c rows w*16..+15
    f32x4 acc2[4] = {};
#pragma unroll
    for (int kk = 0; kk < 2; ++kk) {
        const short8 aw = *(const short8*)&wol[(wave * 16 + l16) * RS + kk * 32 + lh * 8];
#pragma unroll
        for (int ns = 0; ns < 4; ++ns) {
            const short8 bt = *(const short8*)&att[(ns * 16 + l16) * RS + kk * 32 + lh * 8];
            acc2[ns] = __builtin_amdgcn_mfma_f32_16x16x32_bf16(aw, bt, acc2[ns], 0, 0, 0);
        }
    }
    const float g = gamma[0];
#pragma unroll
    for (int r = 0; r < 4; ++r) {
        const int c = wave * 16 + lh * 4 + r;
        const float bc = bo[c];
#pragma unroll
        for (int ns = 0; ns < 4; ++ns) {
            const size_t idx = ((size_t)(b * CIN + c)) * NPIX + i0 + ns * 16 + l16;
            y[idx] = g * (acc2[ns][r] + bc) + x[idx];
        }
    }
}

extern "C" void kernel_launch(void* const* d_in, const int* in_sizes, int n_in,
                              void* d_out, int out_size, void* d_ws, size_t ws_size,
                              hipStream_t stream)
{
    const float* x     = (const float*)d_in[0];
    const float* wq    = (const float*)d_in[1];
    const float* bq    = (const float*)d_in[2];
    const float* wk    = (const float*)d_in[3];
    const float* bk    = (const float*)d_in[4];
    const float* wv    = (const float*)d_in[5];
    const float* bv    = (const float*)d_in[6];
    const float* wo    = (const float*)d_in[7];
    const float* bo    = (const float*)d_in[8];
    const float* gamma = (const float*)d_in[9];
    float* out = (float*)d_out;

    const size_t plane = (size_t)B_ * NPIX * 64;     // 2M elems
    unsigned short* qt = (unsigned short*)d_ws;      // 4 MB
    unsigned short* kt = qt + plane;                 // 4 MB
    unsigned short* vb = kt + plane;                 // 4 MB
    unsigned short* wb = vb + plane;                 // 48 KB (bf16 weights)

    w2bf_kernel<<<dim3(96), 256, 0, stream>>>(wq, wk, wv, wb);
    qkv_mfma_kernel<<<dim3(NPIX / 32, B_), 256, 0, stream>>>(
        x, wb, bq, bk, bv, qt, kt, vb);
    flash_fused_kernel<<<dim3(512), 512, 0, stream>>>(
        qt, kt, vb, wo, bo, gamma, x, out);
}